// Round 2
// baseline (1197.613 us; speedup 1.0000x reference)
//
#include <hip/hip_runtime.h>
#include <hip/hip_bf16.h>

// Problem constants: B=2, T=2048, C=1024, H=16, D=64
#define MHSA_B 2
#define MHSA_T 2048
#define MHSA_C 1024
#define MHSA_H 16
#define MHSA_D 64

typedef __attribute__((ext_vector_type(8))) short bf16x8_t;   // 8 bf16 (4 VGPRs)
typedef __attribute__((ext_vector_type(4))) float f32x4_t;    // 4 fp32 acc

// fp32 -> bf16 round-to-nearest-even (bit pattern)
__device__ __forceinline__ unsigned short f2bf(float f) {
    unsigned int u = __float_as_uint(f);
    u = u + 0x7FFFu + ((u >> 16) & 1u);
    return (unsigned short)(u >> 16);
}

// async global->LDS, 16 B per lane, LDS dest = wave-uniform base + lane*16
__device__ __forceinline__ void gload_lds16(const void* g, void* l) {
    __builtin_amdgcn_global_load_lds(
        (const __attribute__((address_space(1))) void*)g,
        (__attribute__((address_space(3))) void*)l, 16, 0, 0);
}

// ---------------------------------------------------------------------------
// fp32 -> bf16 convert (vectorized)
// ---------------------------------------------------------------------------
__global__ __launch_bounds__(256)
void f32_to_bf16_kernel(const float* __restrict__ in,
                        unsigned short* __restrict__ out, int n4) {
    int i = blockIdx.x * blockDim.x + threadIdx.x;
    const int stride = gridDim.x * blockDim.x;
    for (; i < n4; i += stride) {
        float4 v = *(const float4*)&in[(size_t)i * 4];
        ushort4 u;
        u.x = f2bf(v.x); u.y = f2bf(v.y); u.z = f2bf(v.z); u.w = f2bf(v.w);
        *(ushort4*)&out[(size_t)i * 4] = u;
    }
}

// ---------------------------------------------------------------------------
// Transpose + convert: W fp32 [R][Ncols] -> WT bf16 [Ncols][R]
// block = 256 (32x8), 32x32 tiles
// ---------------------------------------------------------------------------
__global__ __launch_bounds__(256)
void transpose_to_bf16_kernel(const float* __restrict__ W,
                              unsigned short* __restrict__ WT,
                              int R, int Ncols) {
    __shared__ float tile[32][33];
    const int c0 = blockIdx.x * 32;
    const int r0 = blockIdx.y * 32;
    const int tx = threadIdx.x & 31;
    const int ty = threadIdx.x >> 5;   // 0..7
#pragma unroll
    for (int i = 0; i < 32; i += 8)
        tile[ty + i][tx] = W[(size_t)(r0 + ty + i) * Ncols + c0 + tx];
    __syncthreads();
#pragma unroll
    for (int i = 0; i < 32; i += 8)
        WT[(size_t)(c0 + ty + i) * R + r0 + tx] = f2bf(tile[tx][ty + i]);
}

// ---------------------------------------------------------------------------
// bf16 MFMA GEMM (m97 structure): C[M,N] = A[M,K] @ Bt[N,K]^T + bias
// A bf16 row-major, Bt bf16 row-major (pre-transposed B), C fp32.
// BM=BN=128, BK=32, 256 threads = 4 waves (2x2 wave grid, 64x64 each),
// 16x mfma_f32_16x16x32_bf16 per wave per K-step, global_load_lds width 16.
// ---------------------------------------------------------------------------
__global__ __launch_bounds__(256)
void gemm_bf16_mfma(const unsigned short* __restrict__ A,
                    const unsigned short* __restrict__ Bt,
                    const float* __restrict__ bias,
                    float* __restrict__ Cout,
                    int M, int N, int K) {
    __shared__ unsigned short As[128 * 32];   // [row 0..127][k 0..31]
    __shared__ unsigned short Bs[128 * 32];   // [col 0..127][k 0..31]

    const int tid  = threadIdx.x;
    const int lane = tid & 63;
    const int w    = tid >> 6;                // wave 0..3
    const int bm   = blockIdx.y * 128;
    const int bn   = blockIdx.x * 128;
    const int wr   = (w >> 1) * 64;           // wave's row quadrant
    const int wc   = (w & 1) * 64;            // wave's col quadrant

    f32x4_t acc[4][4];
#pragma unroll
    for (int m = 0; m < 4; ++m)
#pragma unroll
        for (int n = 0; n < 4; ++n) acc[m][n] = (f32x4_t){0.f, 0.f, 0.f, 0.f};

    // staging decomposition: call c covers rows c*64 + w*16 + lane/4,
    // k-quarter (lane%4)*8; LDS linear: elem = c*2048 + w*512 + lane*8
    const int rS = lane >> 2;                 // 0..15
    const int kS = (lane & 3) * 8;            // 0,8,16,24

    for (int k0 = 0; k0 < K; k0 += 32) {
        __syncthreads();   // previous iteration's readers done
#pragma unroll
        for (int c = 0; c < 2; ++c) {
            const int row = c * 64 + w * 16 + rS;
            gload_lds16(&A[(size_t)(bm + row) * K + k0 + kS],
                        &As[c * 2048 + w * 512]);
            gload_lds16(&Bt[(size_t)(bn + row) * K + k0 + kS],
                        &Bs[c * 2048 + w * 512]);
        }
        __syncthreads();   // drains vmcnt(0): staged data visible

        bf16x8_t a[4], b[4];
#pragma unroll
        for (int m = 0; m < 4; ++m)
            a[m] = *(const bf16x8_t*)&As[(wr + m * 16 + (lane & 15)) * 32 + (lane >> 4) * 8];
#pragma unroll
        for (int n = 0; n < 4; ++n)
            b[n] = *(const bf16x8_t*)&Bs[(wc + n * 16 + (lane & 15)) * 32 + (lane >> 4) * 8];
#pragma unroll
        for (int m = 0; m < 4; ++m)
#pragma unroll
            for (int n = 0; n < 4; ++n)
                acc[m][n] = __builtin_amdgcn_mfma_f32_16x16x32_bf16(a[m], b[n], acc[m][n], 0, 0, 0);
    }

    // epilogue: C/D layout col=lane&15, row=(lane>>4)*4+reg [m89/m91]
    const int cq = lane >> 4;
    const int cr = lane & 15;
#pragma unroll
    for (int n = 0; n < 4; ++n) {
        const int col = bn + wc + n * 16 + cr;
        const float bv = bias[col];
#pragma unroll
        for (int m = 0; m < 4; ++m) {
#pragma unroll
            for (int r = 0; r < 4; ++r) {
                const int row = bm + wr + m * 16 + cq * 4 + r;
                Cout[(size_t)row * N + col] = acc[m][n][r] + bv;
            }
        }
    }
}

// ---------------------------------------------------------------------------
// Flash-style causal attention, fp32 math.
// qkv fp32 [B*T, 3C]; Q at h*D, K at C+h*D, V at 2C+h*D.
// 256-thread blocks: 4 waves share K/V LDS tiles; thread = one q row.
// Output att written as bf16 [B*T, C] (feeds GEMM2).
// ---------------------------------------------------------------------------
__global__ __launch_bounds__(256)
void attn_fwd_kernel(const float* __restrict__ qkv,
                     unsigned short* __restrict__ attb) {
    constexpr int T = MHSA_T, C = MHSA_C, H = MHSA_H, D = MHSA_D;
    constexpr int C3 = 3 * C;
    constexpr int QB = 256, KB = 64;

    __shared__ float Ks[KB][D];
    __shared__ float Vs[KB][D];

    const int nq = T / QB;                    // 8
    const int qb = blockIdx.x % nq;
    const int h  = (blockIdx.x / nq) % H;
    const int b  = blockIdx.x / (nq * H);
    const int tid = threadIdx.x;
    const int t = qb * QB + tid;              // this thread's query row

    const float* qrow = qkv + (size_t)(b * T + t) * C3 + h * D;
    float q[D], o[D];
#pragma unroll
    for (int d4 = 0; d4 < D / 4; ++d4) {
        float4 qv = *(const float4*)&qrow[d4 * 4];
        q[d4 * 4 + 0] = qv.x * 0.125f;        // 1/sqrt(64)
        q[d4 * 4 + 1] = qv.y * 0.125f;
        q[d4 * 4 + 2] = qv.z * 0.125f;
        q[d4 * 4 + 3] = qv.w * 0.125f;
    }
#pragma unroll
    for (int d = 0; d < D; ++d) o[d] = 0.f;
    float m = -1e30f, l = 0.f;

    const int kend = qb * QB + QB;
    for (int k0 = 0; k0 < kend; k0 += KB) {
        const float* Kbase = qkv + (size_t)(b * T + k0) * C3 + C + h * D;
        const float* Vbase = Kbase + C;
        __syncthreads();
#pragma unroll
        for (int it = 0; it < 4; ++it) {
            const int idx = it * 256 + tid;   // 1024 float4 over 4 iters
            const int r = idx >> 4;
            const int c4 = (idx & 15) * 4;
            *(float4*)&Ks[r][c4] = *(const float4*)&Kbase[(size_t)r * C3 + c4];
            *(float4*)&Vs[r][c4] = *(const float4*)&Vbase[(size_t)r * C3 + c4];
        }
        __syncthreads();

        if (k0 <= t) {                        // tile has at least one unmasked col
            const bool diag = (k0 + KB > t);
            for (int jc = 0; jc < KB; jc += 16) {
                float s[16];
#pragma unroll
                for (int jj = 0; jj < 16; ++jj) {
                    const int j = jc + jj;
                    float4 a4 = {0.f, 0.f, 0.f, 0.f};
#pragma unroll
                    for (int d4 = 0; d4 < D / 4; ++d4) {
                        float4 kv = *(const float4*)&Ks[j][d4 * 4];
                        a4.x += q[d4 * 4 + 0] * kv.x;
                        a4.y += q[d4 * 4 + 1] * kv.y;
                        a4.z += q[d4 * 4 + 2] * kv.z;
                        a4.w += q[d4 * 4 + 3] * kv.w;
                    }
                    float sv = (a4.x + a4.y) + (a4.z + a4.w);
                    if (diag && (k0 + j > t)) sv = -1e30f;
                    s[jj] = sv;
                }
                float mt = m;
#pragma unroll
                for (int jj = 0; jj < 16; ++jj) mt = fmaxf(mt, s[jj]);
                if (mt > m) {
                    const float scale = __expf(m - mt);
                    l *= scale;
#pragma unroll
                    for (int d = 0; d < D; ++d) o[d] *= scale;
                    m = mt;
                }
#pragma unroll
                for (int jj = 0; jj < 16; ++jj) {
                    const float p = __expf(s[jj] - m);
                    l += p;
                    const int j = jc + jj;
#pragma unroll
                    for (int d4 = 0; d4 < D / 4; ++d4) {
                        float4 vv = *(const float4*)&Vs[j][d4 * 4];
                        o[d4 * 4 + 0] += p * vv.x;
                        o[d4 * 4 + 1] += p * vv.y;
                        o[d4 * 4 + 2] += p * vv.z;
                        o[d4 * 4 + 3] += p * vv.w;
                    }
                }
            }
        }
    }

    const float inv = 1.f / l;
    unsigned short* orow = attb + (size_t)(b * T + t) * C + h * D;
#pragma unroll
    for (int d4 = 0; d4 < D / 4; ++d4) {
        ushort4 u;
        u.x = f2bf(o[d4 * 4 + 0] * inv);
        u.y = f2bf(o[d4 * 4 + 1] * inv);
        u.z = f2bf(o[d4 * 4 + 2] * inv);
        u.w = f2bf(o[d4 * 4 + 3] * inv);
        *(ushort4*)&orow[d4 * 4] = u;
    }
}

// ---------------------------------------------------------------------------
// Launch: convert/transpose prep -> bf16 MFMA QKV GEMM -> fp32 attention
//         -> bf16 MFMA out GEMM.
// ws layout (fp32 qkv for attention precision):
//   qkv   fp32 [4096,3072]  48 MiB
//   xb    bf16 [4096,1024]   8 MiB
//   attb  bf16 [4096,1024]   8 MiB
//   wqkvT bf16 [3072,1024]   6 MiB
//   woutT bf16 [1024,1024]   2 MiB   (total 72 MiB)
// ---------------------------------------------------------------------------
extern "C" void kernel_launch(void* const* d_in, const int* in_sizes, int n_in,
                              void* d_out, int out_size, void* d_ws, size_t ws_size,
                              hipStream_t stream) {
    const float* x     = (const float*)d_in[0];
    const float* w_qkv = (const float*)d_in[1];
    const float* b_qkv = (const float*)d_in[2];
    const float* w_out = (const float*)d_in[3];
    const float* b_out = (const float*)d_in[4];
    float* out = (float*)d_out;

    constexpr int BT = MHSA_B * MHSA_T;       // 4096
    constexpr int C  = MHSA_C;                // 1024
    constexpr int C3 = 3 * C;                 // 3072

    float* qkv = (float*)d_ws;
    unsigned short* xb    = (unsigned short*)(qkv + (size_t)BT * C3);
    unsigned short* attb  = xb + (size_t)BT * C;
    unsigned short* wqkvT = attb + (size_t)BT * C;
    unsigned short* woutT = wqkvT + (size_t)C3 * C;

    // prep: x -> bf16; weights -> bf16 transposed
    f32_to_bf16_kernel<<<2048, 256, 0, stream>>>(x, xb, BT * C / 4);
    transpose_to_bf16_kernel<<<dim3(C3 / 32, C / 32), 256, 0, stream>>>(
        w_qkv, wqkvT, C, C3);
    transpose_to_bf16_kernel<<<dim3(C / 32, C / 32), 256, 0, stream>>>(
        w_out, woutT, C, C);

    // 1) qkv = x @ w_qkv + b_qkv   (fp32 out for attention precision)
    gemm_bf16_mfma<<<dim3(C3 / 128, BT / 128), 256, 0, stream>>>(
        xb, wqkvT, b_qkv, qkv, BT, C3, C);

    // 2) causal MHSA (fp32 math, bf16 out)
    attn_fwd_kernel<<<dim3(MHSA_B * MHSA_H * (MHSA_T / 256)), 256, 0, stream>>>(
        qkv, attb);

    // 3) out = att @ w_out + b_out
    gemm_bf16_mfma<<<dim3(C / 128, BT / 128), 256, 0, stream>>>(
        attb, woutT, b_out, out, BT, C, C);
}

// Round 4
// 501.114 us; speedup vs baseline: 2.3899x; 2.3899x over previous
//
#include <hip/hip_runtime.h>
#include <hip/hip_bf16.h>

// Problem constants: B=2, T=2048, C=1024, H=16, D=64
#define MHSA_B 2
#define MHSA_T 2048
#define MHSA_C 1024
#define MHSA_H 16
#define MHSA_D 64

typedef __attribute__((ext_vector_type(8))) short bf16x8_t;          // 8 bf16
typedef __attribute__((ext_vector_type(8))) unsigned short u16x8_t;  // 8 u16
typedef __attribute__((ext_vector_type(4))) float f32x4_t;           // 4 fp32

// fp32 -> bf16 round-to-nearest-even
__device__ __forceinline__ unsigned short f2bf(float f) {
    unsigned int u = __float_as_uint(f);
    u = u + 0x7FFFu + ((u >> 16) & 1u);
    return (unsigned short)(u >> 16);
}

// async global->LDS, 16 B per lane (GEMM staging)
__device__ __forceinline__ void gload_lds16(const void* g, void* l) {
    __builtin_amdgcn_global_load_lds(
        (const __attribute__((address_space(1))) void*)g,
        (__attribute__((address_space(3))) void*)l, 16, 0, 0);
}

__device__ __forceinline__ float rowred_max(float t) {
    t = fmaxf(t, __shfl_xor(t, 1));
    t = fmaxf(t, __shfl_xor(t, 2));
    t = fmaxf(t, __shfl_xor(t, 4));
    t = fmaxf(t, __shfl_xor(t, 8));
    return t;
}
__device__ __forceinline__ float rowred_sum(float t) {
    t += __shfl_xor(t, 1);
    t += __shfl_xor(t, 2);
    t += __shfl_xor(t, 4);
    t += __shfl_xor(t, 8);
    return t;
}

// ---------------------------------------------------------------------------
// fp32 -> bf16 convert (vectorized)
// ---------------------------------------------------------------------------
__global__ __launch_bounds__(256)
void f32_to_bf16_kernel(const float* __restrict__ in,
                        unsigned short* __restrict__ out, int n4) {
    int i = blockIdx.x * blockDim.x + threadIdx.x;
    const int stride = gridDim.x * blockDim.x;
    for (; i < n4; i += stride) {
        float4 v = *(const float4*)&in[(size_t)i * 4];
        ushort4 u;
        u.x = f2bf(v.x); u.y = f2bf(v.y); u.z = f2bf(v.z); u.w = f2bf(v.w);
        *(ushort4*)&out[(size_t)i * 4] = u;
    }
}

// ---------------------------------------------------------------------------
// Transpose + convert: W fp32 [R][Ncols] -> WT bf16 [Ncols][R]
// ---------------------------------------------------------------------------
__global__ __launch_bounds__(256)
void transpose_to_bf16_kernel(const float* __restrict__ W,
                              unsigned short* __restrict__ WT,
                              int R, int Ncols) {
    __shared__ float tile[32][33];
    const int c0 = blockIdx.x * 32;
    const int r0 = blockIdx.y * 32;
    const int tx = threadIdx.x & 31;
    const int ty = threadIdx.x >> 5;
#pragma unroll
    for (int i = 0; i < 32; i += 8)
        tile[ty + i][tx] = W[(size_t)(r0 + ty + i) * Ncols + c0 + tx];
    __syncthreads();
#pragma unroll
    for (int i = 0; i < 32; i += 8)
        WT[(size_t)(c0 + ty + i) * R + r0 + tx] = f2bf(tile[tx][ty + i]);
}

// ---------------------------------------------------------------------------
// bf16 MFMA GEMM (m97 structure): C[M,N] = A[M,K] @ Bt[N,K]^T + bias
// Output fp32 or bf16 (template). HW-verified in round-2 bench.
// ---------------------------------------------------------------------------
template <bool BF16_OUT>
__global__ __launch_bounds__(256)
void gemm_bf16_mfma(const unsigned short* __restrict__ A,
                    const unsigned short* __restrict__ Bt,
                    const float* __restrict__ bias,
                    void* __restrict__ Cout,
                    int M, int N, int K) {
    __shared__ unsigned short As[128 * 32];
    __shared__ unsigned short Bs[128 * 32];

    const int tid  = threadIdx.x;
    const int lane = tid & 63;
    const int w    = tid >> 6;
    const int bm   = blockIdx.y * 128;
    const int bn   = blockIdx.x * 128;
    const int wr   = (w >> 1) * 64;
    const int wc   = (w & 1) * 64;

    f32x4_t acc[4][4];
#pragma unroll
    for (int m = 0; m < 4; ++m)
#pragma unroll
        for (int n = 0; n < 4; ++n) acc[m][n] = (f32x4_t){0.f, 0.f, 0.f, 0.f};

    const int rS = lane >> 2;
    const int kS = (lane & 3) * 8;

    for (int k0 = 0; k0 < K; k0 += 32) {
        __syncthreads();
#pragma unroll
        for (int c = 0; c < 2; ++c) {
            const int row = c * 64 + w * 16 + rS;
            gload_lds16(&A[(size_t)(bm + row) * K + k0 + kS],
                        &As[c * 2048 + w * 512]);
            gload_lds16(&Bt[(size_t)(bn + row) * K + k0 + kS],
                        &Bs[c * 2048 + w * 512]);
        }
        __syncthreads();

        bf16x8_t a[4], b[4];
#pragma unroll
        for (int m = 0; m < 4; ++m)
            a[m] = *(const bf16x8_t*)&As[(wr + m * 16 + (lane & 15)) * 32 + (lane >> 4) * 8];
#pragma unroll
        for (int n = 0; n < 4; ++n)
            b[n] = *(const bf16x8_t*)&Bs[(wc + n * 16 + (lane & 15)) * 32 + (lane >> 4) * 8];
#pragma unroll
        for (int m = 0; m < 4; ++m)
#pragma unroll
            for (int n = 0; n < 4; ++n)
                acc[m][n] = __builtin_amdgcn_mfma_f32_16x16x32_bf16(a[m], b[n], acc[m][n], 0, 0, 0);
    }

    const int cq = lane >> 4;
    const int cr = lane & 15;
#pragma unroll
    for (int n = 0; n < 4; ++n) {
        const int col = bn + wc + n * 16 + cr;
        const float bv = bias[col];
#pragma unroll
        for (int m = 0; m < 4; ++m) {
#pragma unroll
            for (int r = 0; r < 4; ++r) {
                const int row = bm + wr + m * 16 + cq * 4 + r;
                const float val = acc[m][n][r] + bv;
                if constexpr (BF16_OUT)
                    ((unsigned short*)Cout)[(size_t)row * N + col] = f2bf(val);
                else
                    ((float*)Cout)[(size_t)row * N + col] = val;
            }
        }
    }
}

// ---------------------------------------------------------------------------
// MFMA flash attention (causal), bf16 inputs, fp32 softmax/accum.
// qkvb bf16 [B*T][3C]: Q at h*64, K at C+h*64, V at 2C+h*64.
// One 64-thread wave per (b, h, 64-row q-block).
// QK^T: A=Q frags (global), B=K row-major LDS. PV: A=P LDS, B=V^T LDS.
// Softmax on verified C-layout: col=lane&15, row=(lane>>4)*4+reg.
// blockIdx: low 5 bits = (b,h) so each XCD's L2 holds few K/V sets;
// qb descending so longest jobs start first.
// ---------------------------------------------------------------------------
__global__ __launch_bounds__(64)
void attn_mfma_kernel(const unsigned short* __restrict__ qkvb,
                      unsigned short* __restrict__ attb) {
    constexpr int T = MHSA_T, C = MHSA_C, H = MHSA_H;
    constexpr int C3 = 3 * C;
    constexpr int LS = 72;  // LDS row stride in ushorts (144 B: 16B-aligned, conflict-padded)

    __shared__ unsigned short Ks[64 * LS];  // K[kcol][d]
    __shared__ unsigned short Vt[64 * LS];  // V^T[d][kcol]
    __shared__ unsigned short Ps[64 * LS];  // P[q][kcol]

    const int l = threadIdx.x;
    const int c = l & 15;        // frag col / lane-low
    const int g = l >> 4;        // frag k-group / row-group
    const int idx = blockIdx.x;
    const int bh = idx & 31;
    const int h = bh & 15;
    const int b = bh >> 4;
    const int qb = 31 - (idx >> 5);
    const int q0 = qb * 64;
    const size_t rowbase = (size_t)(b * T) * C3;

    // Q fragments: row = m*16 + (lane&15), k(d) = ks*32 + (lane>>4)*8 + j
    bf16x8_t qf[4][2];
    const unsigned short* Qg = qkvb + rowbase + (size_t)q0 * C3 + h * 64;
#pragma unroll
    for (int m = 0; m < 4; ++m)
#pragma unroll
        for (int ks = 0; ks < 2; ++ks)
            qf[m][ks] = *(const bf16x8_t*)(Qg + (size_t)(m * 16 + c) * C3 + ks * 32 + g * 8);

    f32x4_t acc_o[4][4];
#pragma unroll
    for (int m = 0; m < 4; ++m)
#pragma unroll
        for (int dn = 0; dn < 4; ++dn) acc_o[m][dn] = (f32x4_t){0.f, 0.f, 0.f, 0.f};
    float mrun[4][4], lrun[4][4];
#pragma unroll
    for (int m = 0; m < 4; ++m)
#pragma unroll
        for (int j = 0; j < 4; ++j) { mrun[m][j] = -1e30f; lrun[m][j] = 0.f; }

    const unsigned short* Kg = qkvb + rowbase + C + h * 64;
    const unsigned short* Vg = Kg + C;

    const int rs = l >> 3;           // staging row within group of 8
    const int cs8 = (l & 7) * 8;     // staging d-offset (8 elems)

    for (int k0 = 0; k0 <= q0; k0 += 64) {
        __syncthreads();  // protect LDS vs prior iteration's reads
        // ---- stage K (row-major) and V^T (transposed) as bf16 ----
#pragma unroll
        for (int i = 0; i < 8; ++i) {
            const int r = i * 8 + rs;
            u16x8_t kv = *(const u16x8_t*)(Kg + (size_t)(k0 + r) * C3 + cs8);
            *(u16x8_t*)&Ks[r * LS + cs8] = kv;
            u16x8_t vv = *(const u16x8_t*)(Vg + (size_t)(k0 + r) * C3 + cs8);
#pragma unroll
            for (int e = 0; e < 8; ++e)
                Vt[(cs8 + e) * LS + r] = vv[e];
        }
        __syncthreads();  // staged data visible

        // ---- S = Q @ K^T ----
        f32x4_t sA[4][4];
#pragma unroll
        for (int m = 0; m < 4; ++m)
#pragma unroll
            for (int n = 0; n < 4; ++n) sA[m][n] = (f32x4_t){0.f, 0.f, 0.f, 0.f};
#pragma unroll
        for (int ks = 0; ks < 2; ++ks) {
            bf16x8_t kf[4];
#pragma unroll
            for (int n = 0; n < 4; ++n)
                kf[n] = *(const bf16x8_t*)&Ks[(n * 16 + c) * LS + ks * 32 + g * 8];
#pragma unroll
            for (int m = 0; m < 4; ++m)
#pragma unroll
                for (int n = 0; n < 4; ++n)
                    sA[m][n] = __builtin_amdgcn_mfma_f32_16x16x32_bf16(qf[m][ks], kf[n], sA[m][n], 0, 0, 0);
        }

        // ---- scale + causal mask (diagonal tile only) ----
        const bool diag = (k0 == q0);
#pragma unroll
        for (int m = 0; m < 4; ++m)
#pragma unroll
            for (int n = 0; n < 4; ++n)
#pragma unroll
                for (int j = 0; j < 4; ++j) {
                    float sv = sA[m][n][j] * 0.125f;   // 1/sqrt(64)
                    if (diag) {
                        const int col = k0 + n * 16 + c;
                        const int row = q0 + m * 16 + g * 4 + j;
                        sv = (col <= row) ? sv : -1e30f;
                    }
                    sA[m][n][j] = sv;
                }

        // ---- online softmax: rows live in 16-lane groups ----
#pragma unroll
        for (int m = 0; m < 4; ++m)
#pragma unroll
            for (int j = 0; j < 4; ++j) {
                float t = fmaxf(fmaxf(sA[m][0][j], sA[m][1][j]),
                                fmaxf(sA[m][2][j], sA[m][3][j]));
                t = rowred_max(t);
                const float mn = fmaxf(mrun[m][j], t);
                const float scl = __expf(mrun[m][j] - mn);
                mrun[m][j] = mn;
#pragma unroll
                for (int dn = 0; dn < 4; ++dn) acc_o[m][dn][j] *= scl;
                float ps = 0.f;
#pragma unroll
                for (int n = 0; n < 4; ++n) {
                    const float p = __expf(sA[m][n][j] - mn);
                    Ps[(m * 16 + g * 4 + j) * LS + n * 16 + c] = f2bf(p);
                    ps += p;
                }
                ps = rowred_sum(ps);
                lrun[m][j] = lrun[m][j] * scl + ps;
            }
        __syncthreads();  // Ps visible

        // ---- O += P @ V ----
#pragma unroll
        for (int ks = 0; ks < 2; ++ks) {
            bf16x8_t pf[4], vf[4];
#pragma unroll
            for (int m = 0; m < 4; ++m)
                pf[m] = *(const bf16x8_t*)&Ps[(m * 16 + c) * LS + ks * 32 + g * 8];
#pragma unroll
            for (int dn = 0; dn < 4; ++dn)
                vf[dn] = *(const bf16x8_t*)&Vt[(dn * 16 + c) * LS + ks * 32 + g * 8];
#pragma unroll
            for (int m = 0; m < 4; ++m)
#pragma unroll
                for (int dn = 0; dn < 4; ++dn)
                    acc_o[m][dn] = __builtin_amdgcn_mfma_f32_16x16x32_bf16(pf[m], vf[dn], acc_o[m][dn], 0, 0, 0);
        }
    }

    // ---- epilogue: O / l -> attb bf16 ----
    unsigned short* Og = attb + (size_t)(b * T + q0) * C + h * 64;
#pragma unroll
    for (int m = 0; m < 4; ++m)
#pragma unroll
        for (int j = 0; j < 4; ++j) {
            const float inv = 1.f / lrun[m][j];
#pragma unroll
            for (int dn = 0; dn < 4; ++dn)
                Og[(size_t)(m * 16 + g * 4 + j) * C + dn * 16 + c] =
                    f2bf(acc_o[m][dn][j] * inv);
        }
}

// ---------------------------------------------------------------------------
// Launch. ws layout (all bf16 = ushort):
//   qkvb [4096][3072] 24 MiB | xb [4096][1024] 8 | attb [4096][1024] 8
//   wqkvT [3072][1024] 6     | woutT [1024][1024] 2   (total 48 MiB)
// ---------------------------------------------------------------------------
extern "C" void kernel_launch(void* const* d_in, const int* in_sizes, int n_in,
                              void* d_out, int out_size, void* d_ws, size_t ws_size,
                              hipStream_t stream) {
    const float* x     = (const float*)d_in[0];
    const float* w_qkv = (const float*)d_in[1];
    const float* b_qkv = (const float*)d_in[2];
    const float* w_out = (const float*)d_in[3];
    const float* b_out = (const float*)d_in[4];
    float* out = (float*)d_out;

    constexpr int BT = MHSA_B * MHSA_T;  // 4096
    constexpr int C  = MHSA_C;           // 1024
    constexpr int C3 = 3 * C;            // 3072

    unsigned short* qkvb  = (unsigned short*)d_ws;
    unsigned short* xb    = qkvb + (size_t)BT * C3;
    unsigned short* attb  = xb + (size_t)BT * C;
    unsigned short* wqkvT = attb + (size_t)BT * C;
    unsigned short* woutT = wqkvT + (size_t)C3 * C;

    f32_to_bf16_kernel<<<2048, 256, 0, stream>>>(x, xb, BT * C / 4);
    transpose_to_bf16_kernel<<<dim3(C3 / 32, C / 32), 256, 0, stream>>>(
        w_qkv, wqkvT, C, C3);
    transpose_to_bf16_kernel<<<dim3(C / 32, C / 32), 256, 0, stream>>>(
        w_out, woutT, C, C);

    // 1) qkv = x @ w_qkv + b_qkv  -> bf16
    gemm_bf16_mfma<true><<<dim3(C3 / 128, BT / 128), 256, 0, stream>>>(
        xb, wqkvT, b_qkv, qkvb, BT, C3, C);

    // 2) causal MFMA flash attention -> attb bf16
    attn_mfma_kernel<<<dim3(1024), dim3(64), 0, stream>>>(qkvb, attb);

    // 3) out = att @ w_out + b_out -> fp32
    gemm_bf16_mfma<false><<<dim3(C / 128, BT / 128), 256, 0, stream>>>(
        attb, woutT, b_out, out, BT, C, C);
}

// Round 7
// 260.525 us; speedup vs baseline: 4.5969x; 1.9235x over previous
//
#include <hip/hip_runtime.h>
#include <hip/hip_bf16.h>

// Problem constants: B=2, T=2048, C=1024, H=16, D=64
#define MHSA_B 2
#define MHSA_T 2048
#define MHSA_C 1024
#define MHSA_H 16
#define MHSA_D 64

typedef __attribute__((ext_vector_type(8))) short bf16x8_t;          // 8 bf16
typedef __attribute__((ext_vector_type(4))) float f32x4_t;           // 4 fp32

// fp32 -> bf16 round-to-nearest-even
__device__ __forceinline__ unsigned short f2bf(float f) {
    unsigned int u = __float_as_uint(f);
    u = u + 0x7FFFu + ((u >> 16) & 1u);
    return (unsigned short)(u >> 16);
}

// async global->LDS, 16 B per lane (GEMM staging)
__device__ __forceinline__ void gload_lds16(const void* g, void* l) {
    __builtin_amdgcn_global_load_lds(
        (const __attribute__((address_space(1))) void*)g,
        (__attribute__((address_space(3))) void*)l, 16, 0, 0);
}

__device__ __forceinline__ float rowred_max(float t) {
    t = fmaxf(t, __shfl_xor(t, 1));
    t = fmaxf(t, __shfl_xor(t, 2));
    t = fmaxf(t, __shfl_xor(t, 4));
    t = fmaxf(t, __shfl_xor(t, 8));
    return t;
}
__device__ __forceinline__ float rowred_sum(float t) {
    t += __shfl_xor(t, 1);
    t += __shfl_xor(t, 2);
    t += __shfl_xor(t, 4);
    t += __shfl_xor(t, 8);
    return t;
}

// ---------------------------------------------------------------------------
// fp32 -> bf16 convert (vectorized)
// ---------------------------------------------------------------------------
__global__ __launch_bounds__(256)
void f32_to_bf16_kernel(const float* __restrict__ in,
                        unsigned short* __restrict__ out, int n4) {
    int i = blockIdx.x * blockDim.x + threadIdx.x;
    const int stride = gridDim.x * blockDim.x;
    for (; i < n4; i += stride) {
        float4 v = *(const float4*)&in[(size_t)i * 4];
        ushort4 u;
        u.x = f2bf(v.x); u.y = f2bf(v.y); u.z = f2bf(v.z); u.w = f2bf(v.w);
        *(ushort4*)&out[(size_t)i * 4] = u;
    }
}

// ---------------------------------------------------------------------------
// Transpose + convert: W fp32 [R][Ncols] -> WT bf16 [Ncols][R]
// ---------------------------------------------------------------------------
__global__ __launch_bounds__(256)
void transpose_to_bf16_kernel(const float* __restrict__ W,
                              unsigned short* __restrict__ WT,
                              int R, int Ncols) {
    __shared__ float tile[32][33];
    const int c0 = blockIdx.x * 32;
    const int r0 = blockIdx.y * 32;
    const int tx = threadIdx.x & 31;
    const int ty = threadIdx.x >> 5;
#pragma unroll
    for (int i = 0; i < 32; i += 8)
        tile[ty + i][tx] = W[(size_t)(r0 + ty + i) * Ncols + c0 + tx];
    __syncthreads();
#pragma unroll
    for (int i = 0; i < 32; i += 8)
        WT[(size_t)(c0 + ty + i) * R + r0 + tx] = f2bf(tile[tx][ty + i]);
}

// ---------------------------------------------------------------------------
// bf16 MFMA GEMM (m97 structure): C[M,N] = A[M,K] @ Bt[N,K]^T + bias
// MODE 0: fp32 out row-major.
// MODE 1: bf16 out row-major.
// MODE 2 (QKV): bf16 out row-major for cols < 2C; V third (cols >= 2C)
//         written TRANSPOSED to vtb[(b*16+h)*64+d][T] (packed ushort4).
// ---------------------------------------------------------------------------
template <int MODE>
__global__ __launch_bounds__(256)
void gemm_bf16_mfma(const unsigned short* __restrict__ A,
                    const unsigned short* __restrict__ Bt,
                    const float* __restrict__ bias,
                    void* __restrict__ Cout,
                    unsigned short* __restrict__ vtb,
                    int M, int N, int K) {
    __shared__ unsigned short As[128 * 32];
    __shared__ unsigned short Bs[128 * 32];

    const int tid  = threadIdx.x;
    const int lane = tid & 63;
    const int w    = tid >> 6;
    const int bm   = blockIdx.y * 128;
    const int bn   = blockIdx.x * 128;
    const int wr   = (w >> 1) * 64;
    const int wc   = (w & 1) * 64;

    f32x4_t acc[4][4];
#pragma unroll
    for (int m = 0; m < 4; ++m)
#pragma unroll
        for (int n = 0; n < 4; ++n) acc[m][n] = (f32x4_t){0.f, 0.f, 0.f, 0.f};

    const int rS = lane >> 2;
    const int kS = (lane & 3) * 8;

    for (int k0 = 0; k0 < K; k0 += 32) {
        __syncthreads();
#pragma unroll
        for (int c = 0; c < 2; ++c) {
            const int row = c * 64 + w * 16 + rS;
            gload_lds16(&A[(size_t)(bm + row) * K + k0 + kS],
                        &As[c * 2048 + w * 512]);
            gload_lds16(&Bt[(size_t)(bn + row) * K + k0 + kS],
                        &Bs[c * 2048 + w * 512]);
        }
        __syncthreads();

        bf16x8_t a[4], b[4];
#pragma unroll
        for (int m = 0; m < 4; ++m)
            a[m] = *(const bf16x8_t*)&As[(wr + m * 16 + (lane & 15)) * 32 + (lane >> 4) * 8];
#pragma unroll
        for (int n = 0; n < 4; ++n)
            b[n] = *(const bf16x8_t*)&Bs[(wc + n * 16 + (lane & 15)) * 32 + (lane >> 4) * 8];
#pragma unroll
        for (int m = 0; m < 4; ++m)
#pragma unroll
            for (int n = 0; n < 4; ++n)
                acc[m][n] = __builtin_amdgcn_mfma_f32_16x16x32_bf16(a[m], b[n], acc[m][n], 0, 0, 0);
    }

    // epilogue: C/D layout col=lane&15, row=(lane>>4)*4+reg [m89/m91]
    const int cq = lane >> 4;
    const int cr = lane & 15;
#pragma unroll
    for (int n = 0; n < 4; ++n) {
        const int col = bn + wc + n * 16 + cr;
        const float bv = bias[col];
        const int rowb = bm + wr + cq * 4;    // +m*16 +r
#pragma unroll
        for (int m = 0; m < 4; ++m) {
            if (MODE == 2 && col >= 2 * MHSA_C) {
                // V third: write transposed vtb[(b*16+h)*64+d][t], packed x4
                const int vcol = col - 2 * MHSA_C;
                const int h = vcol >> 6;
                const int d = vcol & 63;
                const int tg = rowb + m * 16;         // global token row
                const int bb = tg >> 11;              // /T
                const int tt = tg & (MHSA_T - 1);
                ushort4 u;
                u.x = f2bf(acc[m][n][0] + bv);
                u.y = f2bf(acc[m][n][1] + bv);
                u.z = f2bf(acc[m][n][2] + bv);
                u.w = f2bf(acc[m][n][3] + bv);
                *(ushort4*)&vtb[(size_t)((bb * 16 + h) * 64 + d) * MHSA_T + tt] = u;
            } else {
#pragma unroll
                for (int r = 0; r < 4; ++r) {
                    const int row = rowb + m * 16 + r;
                    const float val = acc[m][n][r] + bv;
                    if (MODE == 0)
                        ((float*)Cout)[(size_t)row * N + col] = val;
                    else
                        ((unsigned short*)Cout)[(size_t)row * N + col] = f2bf(val);
                }
            }
        }
    }
}

// ---------------------------------------------------------------------------
// MFMA flash attention (causal), no K/V LDS staging (L2-resident reads).
// qkvb bf16 [B*T][3C]: Q at h*64, K at C+h*64. vtb bf16 [(b*16+h)*64+d][T].
// One 64-thread wave per (b, h, 32-row q-tile); grid 2048, 8 waves/CU.
// QK^T: A=Q frags (global), B=K rows (global, 16B/lane, L2).
// PV:  A=P (LDS, only LDS use), B=V^T rows (global vtb, 16B/lane, L2).
// Softmax on verified C-layout: col=lane&15, row=(lane>>4)*4+reg.
// blockIdx low 5 bits = (b,h) -> ~4 (b,h) K/V sets per XCD L2 (2MB < 4MB);
// qt descending so longest jobs start first.
// ---------------------------------------------------------------------------
__global__ __launch_bounds__(64, 2)
void attn_mfma_kernel(const unsigned short* __restrict__ qkvb,
                      const unsigned short* __restrict__ vtb,
                      unsigned short* __restrict__ attb) {
    constexpr int T = MHSA_T, C = MHSA_C;
    constexpr int C3 = 3 * C;
    constexpr int LS = 72;                    // P row stride (144 B)

    __shared__ unsigned short Ps[32 * LS];    // P[q][kcol], 4.6 KB

    const int l = threadIdx.x;
    const int c = l & 15;
    const int g = l >> 4;
    const int idx = blockIdx.x;
    const int bh = idx & 31;
    const int h = bh & 15;
    const int b = bh >> 4;
    const int qt = 63 - (idx >> 5);           // longest first
    const int q0 = qt * 32;
    const size_t rowbase = (size_t)(b * T) * C3;

    // Q fragments: row = m*16 + c, d = ks*32 + g*8 + j
    bf16x8_t qf[2][2];
    const unsigned short* Qg = qkvb + rowbase + (size_t)q0 * C3 + h * 64;
#pragma unroll
    for (int m = 0; m < 2; ++m)
#pragma unroll
        for (int ks = 0; ks < 2; ++ks)
            qf[m][ks] = *(const bf16x8_t*)(Qg + (size_t)(m * 16 + c) * C3 + ks * 32 + g * 8);

    f32x4_t acc_o[2][4];
#pragma unroll
    for (int m = 0; m < 2; ++m)
#pragma unroll
        for (int dn = 0; dn < 4; ++dn) acc_o[m][dn] = (f32x4_t){0.f, 0.f, 0.f, 0.f};
    float mrun[2][4], lrun[2][4];
#pragma unroll
    for (int m = 0; m < 2; ++m)
#pragma unroll
        for (int j = 0; j < 4; ++j) { mrun[m][j] = -1e30f; lrun[m][j] = 0.f; }

    const unsigned short* Kg = qkvb + rowbase + C + h * 64;
    const unsigned short* Vg = vtb + (size_t)(bh * 64) * T;

    for (int k0 = 0; k0 <= q0 + 31; k0 += 64) {
        // ---- K fragments straight from global (L2) ----
        bf16x8_t kf[4][2];
#pragma unroll
        for (int n = 0; n < 4; ++n)
#pragma unroll
            for (int ks = 0; ks < 2; ++ks)
                kf[n][ks] = *(const bf16x8_t*)(Kg + (size_t)(k0 + n * 16 + c) * C3 + ks * 32 + g * 8);

        // ---- S = Q @ K^T ----
        f32x4_t sA[2][4];
#pragma unroll
        for (int m = 0; m < 2; ++m)
#pragma unroll
            for (int n = 0; n < 4; ++n) sA[m][n] = (f32x4_t){0.f, 0.f, 0.f, 0.f};
#pragma unroll
        for (int ks = 0; ks < 2; ++ks)
#pragma unroll
            for (int m = 0; m < 2; ++m)
#pragma unroll
                for (int n = 0; n < 4; ++n)
                    sA[m][n] = __builtin_amdgcn_mfma_f32_16x16x32_bf16(qf[m][ks], kf[n][ks], sA[m][n], 0, 0, 0);

        // ---- V^T fragments issued now; latency hides under softmax ----
        bf16x8_t vf[4][2];
#pragma unroll
        for (int dn = 0; dn < 4; ++dn)
#pragma unroll
            for (int ks = 0; ks < 2; ++ks)
                vf[dn][ks] = *(const bf16x8_t*)(Vg + (size_t)(dn * 16 + c) * T + k0 + ks * 32 + g * 8);

        // ---- scale + causal mask (last tile only) ----
        const bool diag = (k0 + 64 > q0);
#pragma unroll
        for (int m = 0; m < 2; ++m)
#pragma unroll
            for (int n = 0; n < 4; ++n)
#pragma unroll
                for (int j = 0; j < 4; ++j) {
                    float sv = sA[m][n][j] * 0.125f;   // 1/sqrt(64)
                    if (diag) {
                        const int col = k0 + n * 16 + c;
                        const int row = q0 + m * 16 + g * 4 + j;
                        sv = (col <= row) ? sv : -1e30f;
                    }
                    sA[m][n][j] = sv;
                }

        // ---- online softmax: rows live in 16-lane groups ----
#pragma unroll
        for (int m = 0; m < 2; ++m)
#pragma unroll
            for (int j = 0; j < 4; ++j) {
                float t = fmaxf(fmaxf(sA[m][0][j], sA[m][1][j]),
                                fmaxf(sA[m][2][j], sA[m][3][j]));
                t = rowred_max(t);
                const float mn = fmaxf(mrun[m][j], t);
                const float scl = __expf(mrun[m][j] - mn);
                mrun[m][j] = mn;
#pragma unroll
                for (int dn = 0; dn < 4; ++dn) acc_o[m][dn][j] *= scl;
                float ps = 0.f;
#pragma unroll
                for (int n = 0; n < 4; ++n) {
                    const float p = __expf(sA[m][n][j] - mn);
                    Ps[(m * 16 + g * 4 + j) * LS + n * 16 + c] = f2bf(p);
                    ps += p;
                }
                ps = rowred_sum(ps);
                lrun[m][j] = lrun[m][j] * scl + ps;
            }
        __syncthreads();   // single wave: compiles to a cheap lgkm drain

        // ---- O += P @ V ----
#pragma unroll
        for (int ks = 0; ks < 2; ++ks) {
            bf16x8_t pf[2];
#pragma unroll
            for (int m = 0; m < 2; ++m)
                pf[m] = *(const bf16x8_t*)&Ps[(m * 16 + c) * LS + ks * 32 + g * 8];
#pragma unroll
            for (int m = 0; m < 2; ++m)
#pragma unroll
                for (int dn = 0; dn < 4; ++dn)
                    acc_o[m][dn] = __builtin_amdgcn_mfma_f32_16x16x32_bf16(pf[m], vf[dn][ks], acc_o[m][dn], 0, 0, 0);
        }
    }

    // ---- epilogue: O / l -> attb bf16 ----
    unsigned short* Og = attb + (size_t)(b * T + q0) * C + h * 64;
#pragma unroll
    for (int m = 0; m < 2; ++m)
#pragma unroll
        for (int j = 0; j < 4; ++j) {
            const float inv = 1.f / lrun[m][j];
#pragma unroll
            for (int dn = 0; dn < 4; ++dn)
                Og[(size_t)(m * 16 + g * 4 + j) * C + dn * 16 + c] =
                    f2bf(acc_o[m][dn][j] * inv);
        }
}

// ---------------------------------------------------------------------------
// Launch. ws layout (all bf16 = ushort):
//   qkvb [4096][3072] 24 MiB (V third unwritten/unused)
//   vtb  [2048][2048]  8 MiB (V transposed per (b,h): [64 d][2048 t])
//   xb   [4096][1024]  8 MiB | attb [4096][1024] 8 MiB
//   wqkvT [3072][1024] 6 MiB | woutT [1024][1024] 2 MiB   (56 MiB total)
// ---------------------------------------------------------------------------
extern "C" void kernel_launch(void* const* d_in, const int* in_sizes, int n_in,
                              void* d_out, int out_size, void* d_ws, size_t ws_size,
                              hipStream_t stream) {
    const float* x     = (const float*)d_in[0];
    const float* w_qkv = (const float*)d_in[1];
    const float* b_qkv = (const float*)d_in[2];
    const float* w_out = (const float*)d_in[3];
    const float* b_out = (const float*)d_in[4];
    float* out = (float*)d_out;

    constexpr int BT = MHSA_B * MHSA_T;  // 4096
    constexpr int C  = MHSA_C;           // 1024
    constexpr int C3 = 3 * C;            // 3072

    unsigned short* qkvb  = (unsigned short*)d_ws;
    unsigned short* vtb   = qkvb + (size_t)BT * C3;
    unsigned short* xb    = vtb + (size_t)2048 * 2048;
    unsigned short* attb  = xb + (size_t)BT * C;
    unsigned short* wqkvT = attb + (size_t)BT * C;
    unsigned short* woutT = wqkvT + (size_t)C3 * C;

    f32_to_bf16_kernel<<<2048, 256, 0, stream>>>(x, xb, BT * C / 4);
    transpose_to_bf16_kernel<<<dim3(C3 / 32, C / 32), 256, 0, stream>>>(
        w_qkv, wqkvT, C, C3);
    transpose_to_bf16_kernel<<<dim3(C / 32, C / 32), 256, 0, stream>>>(
        w_out, woutT, C, C);

    // 1) qkv = x @ w_qkv + b_qkv -> bf16 (Q,K row-major; V transposed to vtb)
    gemm_bf16_mfma<2><<<dim3(C3 / 128, BT / 128), 256, 0, stream>>>(
        xb, wqkvT, b_qkv, qkvb, vtb, BT, C3, C);

    // 2) causal MFMA flash attention -> attb bf16
    attn_mfma_kernel<<<dim3(2048), dim3(64), 0, stream>>>(qkvb, vtb, attb);

    // 3) out = att @ w_out + b_out -> fp32
    gemm_bf16_mfma<0><<<dim3(C / 128, BT / 128), 256, 0, stream>>>(
        attb, woutT, b_out, out, nullptr, BT, C, C);
}